// Round 1
// baseline (102.559 us; speedup 1.0000x reference)
//
#include <hip/hip_runtime.h>
#include <math.h>

// Problem: B=2, T=4096, N=4, DIM=2048
//   rows = B*T*N = 32768 rows of DIM f32
//   out  = H_pre [32768] ++ H_post [32768] ++ H_res [B,T,4,4] (131072)  (f32)
#define DIM     2048
#define NROWS   32768
#define EPS_RMS 1e-6f

// 6 folded theta vectors in LDS: [0]=w*theta_pre, [1]=w*theta_post, [2..5]=w*theta_res[i]
#define NTH 6

__global__ __launch_bounds__(256) void hcmaps_kernel(
    const float* __restrict__ x,          // [NROWS, DIM]
    const float* __restrict__ w,          // [DIM]
    const float* __restrict__ alpha_pre_p,
    const float* __restrict__ alpha_post_p,
    const float* __restrict__ alpha_res_p,
    const float* __restrict__ theta_pre,  // [DIM]
    const float* __restrict__ theta_post, // [DIM]
    const float* __restrict__ theta_res,  // [4, DIM]
    const float* __restrict__ b_pre,      // [4]
    const float* __restrict__ b_post,     // [4]
    const float* __restrict__ b_res,      // [16] row-major [i][n]
    float* __restrict__ out)              // [196608]
{
    __shared__ float s_wt[NTH * DIM];     // 48 KiB

    // ---- fill LDS with w*theta (once per block) ----
    for (int c = threadIdx.x * 4; c < DIM; c += 256 * 4) {
        const float4 wv = *(const float4*)(w + c);
        const float4 tp = *(const float4*)(theta_pre + c);
        const float4 tq = *(const float4*)(theta_post + c);
        *(float4*)(s_wt + 0 * DIM + c) =
            make_float4(wv.x * tp.x, wv.y * tp.y, wv.z * tp.z, wv.w * tp.w);
        *(float4*)(s_wt + 1 * DIM + c) =
            make_float4(wv.x * tq.x, wv.y * tq.y, wv.z * tq.z, wv.w * tq.w);
#pragma unroll
        for (int i = 0; i < 4; ++i) {
            const float4 tr = *(const float4*)(theta_res + i * DIM + c);
            *(float4*)(s_wt + (2 + i) * DIM + c) =
                make_float4(wv.x * tr.x, wv.y * tr.y, wv.z * tr.z, wv.w * tr.w);
        }
    }
    __syncthreads();

    const int lane   = threadIdx.x & 63;
    const int wave   = blockIdx.x * (blockDim.x >> 6) + (threadIdx.x >> 6);
    const int nwaves = gridDim.x * (blockDim.x >> 6);

    const float apre  = alpha_pre_p[0];
    const float apost = alpha_post_p[0];
    const float ares  = alpha_res_p[0];

    // each wave processes a pair of consecutive rows per iteration
    for (int p = wave; p < (NROWS / 2); p += nwaves) {
        const int r0 = p * 2;
        const float4* __restrict__ x0 = (const float4*)(x + (size_t)r0 * DIM);
        const float4* __restrict__ x1 = (const float4*)(x + (size_t)(r0 + 1) * DIM);

        // load both rows' slices up front (coalesced float4, 16 loads in flight)
        float4 xa[8], xb[8];
#pragma unroll
        for (int j = 0; j < 8; ++j) {
            xa[j] = x0[j * 64 + lane];
            xb[j] = x1[j * 64 + lane];
        }

        float ssa = 0.f, ssb = 0.f;
        float da0 = 0.f, da1 = 0.f, da2 = 0.f, da3 = 0.f, da4 = 0.f, da5 = 0.f;
        float db0 = 0.f, db1 = 0.f, db2 = 0.f, db3 = 0.f, db4 = 0.f, db5 = 0.f;

#pragma unroll
        for (int j = 0; j < 8; ++j) {
            const int c = (j * 64 + lane) * 4;
            const float4 A = xa[j];
            const float4 Bv = xb[j];
            ssa += A.x * A.x + A.y * A.y + A.z * A.z + A.w * A.w;
            ssb += Bv.x * Bv.x + Bv.y * Bv.y + Bv.z * Bv.z + Bv.w * Bv.w;

            float4 t;
            t = *(const float4*)(s_wt + 0 * DIM + c);
            da0 += t.x * A.x + t.y * A.y + t.z * A.z + t.w * A.w;
            db0 += t.x * Bv.x + t.y * Bv.y + t.z * Bv.z + t.w * Bv.w;
            t = *(const float4*)(s_wt + 1 * DIM + c);
            da1 += t.x * A.x + t.y * A.y + t.z * A.z + t.w * A.w;
            db1 += t.x * Bv.x + t.y * Bv.y + t.z * Bv.z + t.w * Bv.w;
            t = *(const float4*)(s_wt + 2 * DIM + c);
            da2 += t.x * A.x + t.y * A.y + t.z * A.z + t.w * A.w;
            db2 += t.x * Bv.x + t.y * Bv.y + t.z * Bv.z + t.w * Bv.w;
            t = *(const float4*)(s_wt + 3 * DIM + c);
            da3 += t.x * A.x + t.y * A.y + t.z * A.z + t.w * A.w;
            db3 += t.x * Bv.x + t.y * Bv.y + t.z * Bv.z + t.w * Bv.w;
            t = *(const float4*)(s_wt + 4 * DIM + c);
            da4 += t.x * A.x + t.y * A.y + t.z * A.z + t.w * A.w;
            db4 += t.x * Bv.x + t.y * Bv.y + t.z * Bv.z + t.w * Bv.w;
            t = *(const float4*)(s_wt + 5 * DIM + c);
            da5 += t.x * A.x + t.y * A.y + t.z * A.z + t.w * A.w;
            db5 += t.x * Bv.x + t.y * Bv.y + t.z * Bv.z + t.w * Bv.w;
        }

        // butterfly reduce 14 scalars across the 64-lane wave
#pragma unroll
        for (int off = 32; off > 0; off >>= 1) {
            ssa += __shfl_xor(ssa, off);
            ssb += __shfl_xor(ssb, off);
            da0 += __shfl_xor(da0, off);
            da1 += __shfl_xor(da1, off);
            da2 += __shfl_xor(da2, off);
            da3 += __shfl_xor(da3, off);
            da4 += __shfl_xor(da4, off);
            da5 += __shfl_xor(da5, off);
            db0 += __shfl_xor(db0, off);
            db1 += __shfl_xor(db1, off);
            db2 += __shfl_xor(db2, off);
            db3 += __shfl_xor(db3, off);
            db4 += __shfl_xor(db4, off);
            db5 += __shfl_xor(db5, off);
        }

        // epilogue: lane 0 writes row r0, lane 1 writes row r0+1
        if (lane == 0) {
            const int r = r0;
            const int n = r & 3;
            const int rbt = r >> 2;
            const float rstd = rsqrtf(ssa * (1.0f / DIM) + EPS_RMS);
            out[r]         = apre  * tanhf(da0 * rstd) + b_pre[n];
            out[32768 + r] = apost * tanhf(da1 * rstd) + b_post[n];
            float* res = out + 65536 + rbt * 16 + n;
            res[0]  = ares * tanhf(da2 * rstd) + b_res[0 * 4 + n];
            res[4]  = ares * tanhf(da3 * rstd) + b_res[1 * 4 + n];
            res[8]  = ares * tanhf(da4 * rstd) + b_res[2 * 4 + n];
            res[12] = ares * tanhf(da5 * rstd) + b_res[3 * 4 + n];
        } else if (lane == 1) {
            const int r = r0 + 1;
            const int n = r & 3;
            const int rbt = r >> 2;
            const float rstd = rsqrtf(ssb * (1.0f / DIM) + EPS_RMS);
            out[r]         = apre  * tanhf(db0 * rstd) + b_pre[n];
            out[32768 + r] = apost * tanhf(db1 * rstd) + b_post[n];
            float* res = out + 65536 + rbt * 16 + n;
            res[0]  = ares * tanhf(db2 * rstd) + b_res[0 * 4 + n];
            res[4]  = ares * tanhf(db3 * rstd) + b_res[1 * 4 + n];
            res[8]  = ares * tanhf(db4 * rstd) + b_res[2 * 4 + n];
            res[12] = ares * tanhf(db5 * rstd) + b_res[3 * 4 + n];
        }
    }
}

extern "C" void kernel_launch(void* const* d_in, const int* in_sizes, int n_in,
                              void* d_out, int out_size, void* d_ws, size_t ws_size,
                              hipStream_t stream) {
    const float* x          = (const float*)d_in[0];
    const float* rms_weight = (const float*)d_in[1];
    const float* alpha_pre  = (const float*)d_in[2];
    const float* alpha_post = (const float*)d_in[3];
    const float* alpha_res  = (const float*)d_in[4];
    const float* theta_pre  = (const float*)d_in[5];
    const float* theta_post = (const float*)d_in[6];
    const float* theta_res  = (const float*)d_in[7];
    const float* b_pre      = (const float*)d_in[8];
    const float* b_post     = (const float*)d_in[9];
    const float* b_res      = (const float*)d_in[10];
    float* out = (float*)d_out;

    dim3 grid(2048);
    dim3 block(256);
    hipLaunchKernelGGL(hcmaps_kernel, grid, block, 0, stream,
                       x, rms_weight, alpha_pre, alpha_post, alpha_res,
                       theta_pre, theta_post, theta_res,
                       b_pre, b_post, b_res, out);
}